// Round 5
// baseline (27.243 us; speedup 1.0000x reference)
//
#include <hip/hip_runtime.h>

#define L2048 2048
#define BIGV 1e12f

// f(r) = WALL * softplus((R0-r)/DELTA) * smoothstep_down(r; 8, 10)
// softplus(x) = ln2 * log2(1 + exp2(x*log2e));  x = (4-r)*5
// Triangular (j >= i+2) counted once -> final scale 2 * WALL * ln2.

__device__ __forceinline__ float row_sum(const float4* __restrict__ pts,
                                         int i, int j0, int n, int lane) {
    const float4 Pi = pts[i];                 // uniform address -> LDS broadcast
    const float xi = Pi.x, yi = Pi.y, zi = Pi.z;
    float acc = 0.0f;
    const int chunks = (n + 63) >> 6;
    #pragma unroll 4
    for (int c = 0; c < chunks; ++c) {
        const int j  = j0 + c * 64 + lane;
        const int jj = (j < L2048) ? j : (L2048 - 1);
        const float4 P = pts[jj];             // one ds_read_b128, conflict-free
        const float dx = P.x - xi, dy = P.y - yi, dz = P.z - zi;
        float d2 = dx * dx;
        d2 = fmaf(dy, dy, d2);
        d2 = fmaf(dz, dz, d2);
        if (j >= L2048) d2 = BIGV;            // tail mask -> f == 0 arithmetically

        const float r  = sqrtf(d2);
        const float e  = __builtin_amdgcn_exp2f(fmaf(r, -7.2134752f, 28.8539008f));
        const float lg = __builtin_amdgcn_logf(1.0f + e);   // log2; 0 for far pairs
        float t = fmaf(r, 0.5f, -4.0f);       // smoothstep 1@r=8 -> 0@r>=10
        t = fminf(fmaxf(t, 0.0f), 1.0f);
        const float sw = fmaf(-t * t, fmaf(-2.0f, t, 3.0f), 1.0f);
        acc = fmaf(lg, sw, acc);
    }
    return acc;
}

__global__ __launch_bounds__(256) void pair_energy_kernel(const float* __restrict__ R,
                                                          float* __restrict__ ws) {
    __shared__ float4 pts[L2048];             // xyz + pad, 32 KB

    const int wave = threadIdx.x >> 6;
    const int lane = threadIdx.x & 63;
    const int unit = blockIdx.x * 4 + wave;   // 1024 units per batch
    const int b = unit >> 10;
    const int u = unit & 1023;                // u==1023 is a no-op unit
    const float* Rb = R + (size_t)b * (L2048 * 3);

    // ---- stage batch coords into LDS as padded AoS (16B/point), one-time ----
    {
        float* dst = (float*)pts;
        const int t = threadIdx.x;
        #pragma unroll
        for (int k = 0; k < 6; ++k) {
            const int f4 = (t + 256 * k) * 4;               // dword index, 16B-aligned
            const float4 v = *(const float4*)(Rb + f4);     // contiguous, coalesced
            #pragma unroll
            for (int c = 0; c < 4; ++c) {
                const int f = f4 + c;
                const int p = f / 3;                        // const-div -> magic mul
                const int comp = f - p * 3;
                dst[p * 4 + comp] = ((const float*)&v)[c];  // static index, no scratch
            }
        }
    }
    __syncthreads();

    float acc = 0.0f;
    if (u < 1023) {
        // row A: i = u,      j in [u+2, 2047]      (2046-u pairs)
        acc  = row_sum(pts, u, u + 2, 2046 - u, lane);
        // row B: i = 2045-u, j in [2047-u, 2047]   (u+1 pairs); total = 2047, balanced
        acc += row_sum(pts, 2045 - u, 2047 - u, u + 1, lane);
    }

    #pragma unroll
    for (int off = 32; off > 0; off >>= 1) acc += __shfl_xor(acc, off, 64);

    __shared__ float sp[4];
    if (lane == 0) sp[wave] = acc;
    __syncthreads();
    if (threadIdx.x == 0)
        ws[blockIdx.x] = sp[0] + sp[1] + sp[2] + sp[3];     // plain store, no atomics
}

__global__ __launch_bounds__(256) void reduce_kernel(const float* __restrict__ ws,
                                                     float* __restrict__ out) {
    const int wave = threadIdx.x >> 6;
    const int lane = threadIdx.x & 63;
    float v = ws[blockIdx.x * 256 + threadIdx.x];
    #pragma unroll
    for (int off = 32; off > 0; off >>= 1) v += __shfl_xor(v, off, 64);
    __shared__ float sp[4];
    if (lane == 0) sp[wave] = v;
    __syncthreads();
    if (threadIdx.x == 0)
        out[blockIdx.x] = (sp[0] + sp[1] + sp[2] + sp[3]) * 13.86294361f; // 2*WALL*ln2
}

extern "C" void kernel_launch(void* const* d_in, const int* in_sizes, int n_in,
                              void* d_out, int out_size, void* d_ws, size_t ws_size,
                              hipStream_t stream) {
    (void)n_in; (void)out_size; (void)ws_size;
    const float* R = (const float*)d_in[0];
    float* out = (float*)d_out;
    float* ws  = (float*)d_ws;

    const int B = in_sizes[0] / (L2048 * 3);
    pair_energy_kernel<<<B * 256, 256, 0, stream>>>(R, ws);   // 1024 row-pair units / batch
    reduce_kernel<<<B, 256, 0, stream>>>(ws, out);            // 256 partials / batch
}

// Round 6
// 17.588 us; speedup vs baseline: 1.5490x; 1.5490x over previous
//
#include <hip/hip_runtime.h>

#define LPTS 2048
#define BIGV 1e12f

// f(r) = WALL * softplus((R0-r)/DELTA) * sw(r).  sw dropped: at r>=8 where sw<1,
// f <= 2e-8 -> replacing sw by 1 changes the sum by <1e-5 (tolerance 2.7e4).
// softplus in log2 domain: ln2 * log2(1 + exp2(28.8539008 - 7.2134752*r)).
// Triangle counted once -> final scale 2 * WALL * ln2 = 13.86294361.

__global__ __launch_bounds__(512, 8) void pair_energy_kernel(const float* __restrict__ R,
                                                             float* __restrict__ ws) {
    __shared__ float lds[LPTS * 3];          // packed xyz, 24 KB

    const int t    = threadIdx.x;
    const int wave = t >> 6;
    const int lane = t & 63;
    const int bb   = blockIdx.x >> 7;        // 128 blocks per batch
    const float* Rb = R + (size_t)bb * (LPTS * 3);

    // ---- stage 6144 dwords: 3 x float4 per thread, fully coalesced, linear LDS ----
    #pragma unroll
    for (int k = 0; k < 3; ++k) {
        const int f4 = t + 512 * k;
        ((float4*)lds)[f4] = ((const float4*)Rb)[f4];
    }
    __syncthreads();

    // unit u in [0,1023]; u pairs row A (i=u, nA=2046-u) with row B (i=2045-u, nB=u+1)
    const int u = __builtin_amdgcn_readfirstlane((blockIdx.x * 8 + wave) & 1023);

    float acc = 0.0f;
    if (u < 1023) {                          // u==1023 duplicates u==1022's row B
        const int nA   = 2046 - u;           // SGPR
        const int offA = u + 2;              // SGPR
        const int iA3 = u * 3, iB3 = (2045 - u) * 3;
        const float xa = lds[iA3], ya = lds[iA3 + 1], za = lds[iA3 + 2];
        const float xb = lds[iB3], yb = lds[iB3 + 1], zb = lds[iB3 + 2];

        #pragma unroll 4
        for (int c = 0; c < 32; ++c) {       // fixed trip count: p covers [0,2047]
            const int p = c * 64 + lane;
            const bool isA = p < nA;
            const float xi = isA ? xa : xb;
            const float yi = isA ? ya : yb;
            const float zi = isA ? za : zb;
            const int j = p + (isA ? offA : 1);   // row A: u+2+p ; row B: p+1
            const int j3 = j * 3;
            const float dx = lds[j3]     - xi;
            const float dy = lds[j3 + 1] - yi;
            const float dz = lds[j3 + 2] - zi;
            float d2 = dx * dx;
            d2 = fmaf(dy, dy, d2);
            d2 = fmaf(dz, dz, d2);
            if (p > 2046) d2 = BIGV;              // only possible pair index OOB
            const float r = __builtin_amdgcn_sqrtf(d2);               // raw v_sqrt_f32
            const float e = __builtin_amdgcn_exp2f(fmaf(r, -7.2134752f, 28.8539008f));
            acc += __builtin_amdgcn_logf(1.0f + e);                   // v_log_f32 (log2)
        }
    }

    #pragma unroll
    for (int off = 32; off > 0; off >>= 1) acc += __shfl_xor(acc, off, 64);

    __shared__ float sp[8];
    if (lane == 0) sp[wave] = acc;
    __syncthreads();
    if (t == 0) {
        float s = sp[0];
        #pragma unroll
        for (int w = 1; w < 8; ++w) s += sp[w];
        ws[blockIdx.x] = s;                   // plain store, 1024 distinct addresses
    }
}

__global__ __launch_bounds__(128) void reduce_kernel(const float* __restrict__ ws,
                                                     float* __restrict__ out) {
    const int t = threadIdx.x;
    const int wave = t >> 6;
    const int lane = t & 63;
    float v = ws[blockIdx.x * 128 + t];
    #pragma unroll
    for (int off = 32; off > 0; off >>= 1) v += __shfl_xor(v, off, 64);
    __shared__ float sp[2];
    if (lane == 0) sp[wave] = v;
    __syncthreads();
    if (t == 0) out[blockIdx.x] = (sp[0] + sp[1]) * 13.86294361f;  // 2*WALL*ln2
}

extern "C" void kernel_launch(void* const* d_in, const int* in_sizes, int n_in,
                              void* d_out, int out_size, void* d_ws, size_t ws_size,
                              hipStream_t stream) {
    (void)n_in; (void)out_size; (void)ws_size;
    const float* R = (const float*)d_in[0];
    float* out = (float*)d_out;
    float* ws  = (float*)d_ws;

    const int B = in_sizes[0] / (LPTS * 3);
    pair_energy_kernel<<<B * 128, 512, 0, stream>>>(R, ws);  // 8 row-pair units / block
    reduce_kernel<<<B, 128, 0, stream>>>(ws, out);           // 128 partials / batch
}

// Round 7
// 16.221 us; speedup vs baseline: 1.6795x; 1.0842x over previous
//
#include <hip/hip_runtime.h>

typedef float v2f __attribute__((ext_vector_type(2)));

#define LPTS 2048
#define BIGV 1e12f

// f(r) = WALL * softplus((4-r)/0.2); smoothstep dropped (f<=2e-8 where sw<1).
// softplus in log2 domain: ln2 * log2(1 + exp2(28.8539008 - 7.2134752*r)).
// Triangle counted once -> final scale 2 * WALL * ln2 = 13.86294361.

__device__ __forceinline__ float pterm(float d2) {
    const float r = __builtin_amdgcn_sqrtf(d2);
    const float e = __builtin_amdgcn_exp2f(fmaf(r, -7.2134752f, 28.8539008f));
    return __builtin_amdgcn_logf(1.0f + e);   // v_log_f32 == log2; 0 for far pairs
}

// Row i vs j in [j0, 2047], SoA LDS, pairs {jb, jb+1} anchored at the top so
// every ds_read_b64 is 8B-aligned. j0/n are wave-uniform (u is readfirstlane'd).
__device__ __forceinline__ void row_seg(const float* __restrict__ sx, int j0, int lane,
                                        float xi, float yi, float zi,
                                        float& a0, float& a1) {
    const int n     = 2048 - j0;     // uniform
    const int fullc = n >> 7;        // uniform: chunks with no masking at all
    const int rem   = n & 127;       // uniform
    const int base  = 2046 - 2 * lane;             // even
    const v2f xi2 = {xi, xi}, yi2 = {yi, yi}, zi2 = {zi, zi};

    for (int c = 0; c < fullc; ++c) {
        const int jb = base - 128 * c;             // lowest jb = j0 + rem >= j0
        const v2f xv = *(const v2f*)(sx + jb);          // ds_read_b64
        const v2f yv = *(const v2f*)(sx + LPTS + jb);   // same vaddr, offset +8192
        const v2f zv = *(const v2f*)(sx + 2 * LPTS + jb); // offset +16384
        const v2f dx = xv - xi2, dy = yv - yi2, dz = zv - zi2;
        v2f d2 = dx * dx;
        d2 = __builtin_elementwise_fma(dy, dy, d2);
        d2 = __builtin_elementwise_fma(dz, dz, d2);
        a0 += pterm(d2.x);
        a1 += pterm(d2.y);
    }
    if (rem) {                                     // single masked boundary chunk
        const int jbu = base - 128 * fullc;        // even; may be < j0 or < 0
        const int jcl = (jbu > 0) ? jbu : 0;       // clamp for LDS safety (stays even)
        const v2f xv = *(const v2f*)(sx + jcl);
        const v2f yv = *(const v2f*)(sx + LPTS + jcl);
        const v2f zv = *(const v2f*)(sx + 2 * LPTS + jcl);
        const v2f dx = xv - xi2, dy = yv - yi2, dz = zv - zi2;
        v2f d2 = dx * dx;
        d2 = __builtin_elementwise_fma(dy, dy, d2);
        d2 = __builtin_elementwise_fma(dz, dz, d2);
        const float d2x = (jbu     >= j0) ? d2.x : BIGV;
        const float d2y = (jbu + 1 >= j0) ? d2.y : BIGV;
        a0 += pterm(d2x);
        a1 += pterm(d2y);
    }
}

__global__ __launch_bounds__(512, 8) void pair_energy_kernel(const float* __restrict__ R,
                                                             float* __restrict__ ws) {
    __shared__ float lds[3 * LPTS];              // SoA x|y|z, 24 KB

    const int t    = threadIdx.x;
    const int wave = t >> 6;
    const int lane = t & 63;
    const int bb   = blockIdx.x >> 7;            // 128 blocks per batch
    const float* Rb = R + (size_t)bb * (LPTS * 3);

    // stage: 3 coalesced float4 loads per thread, repacked AoS->SoA
    #pragma unroll
    for (int k = 0; k < 3; ++k) {
        const int f4 = t + 512 * k;
        const float4 v = ((const float4*)Rb)[f4];
        #pragma unroll
        for (int c = 0; c < 4; ++c) {
            const unsigned f = 4u * (unsigned)f4 + c;
            const unsigned p = f / 3u;           // magic-mul div
            const unsigned comp = f - 3u * p;
            lds[comp * LPTS + p] = ((const float*)&v)[c];
        }
    }
    __syncthreads();

    const int u = __builtin_amdgcn_readfirstlane((blockIdx.x * 8 + wave) & 1023);

    float a0 = 0.0f, a1 = 0.0f;
    if (u < 1023) {                              // u==1023 is a no-op unit
        const int iA = u, iB = 2045 - u;
        // row A: j in [u+2, 2047] (2046-u pairs); row B: j in [2047-u, 2047] (u+1)
        row_seg(lds, u + 2,    lane, lds[iA], lds[LPTS + iA], lds[2 * LPTS + iA], a0, a1);
        row_seg(lds, 2047 - u, lane, lds[iB], lds[LPTS + iB], lds[2 * LPTS + iB], a0, a1);
    }

    float acc = a0 + a1;
    #pragma unroll
    for (int off = 32; off > 0; off >>= 1) acc += __shfl_xor(acc, off, 64);

    __shared__ float sp[8];
    if (lane == 0) sp[wave] = acc;
    __syncthreads();
    if (t == 0) {
        float s = sp[0];
        #pragma unroll
        for (int w = 1; w < 8; ++w) s += sp[w];
        ws[blockIdx.x] = s;                       // plain store, no atomics
    }
}

__global__ __launch_bounds__(128) void reduce_kernel(const float* __restrict__ ws,
                                                     float* __restrict__ out) {
    const int t = threadIdx.x;
    const int wave = t >> 6;
    const int lane = t & 63;
    float v = ws[blockIdx.x * 128 + t];
    #pragma unroll
    for (int off = 32; off > 0; off >>= 1) v += __shfl_xor(v, off, 64);
    __shared__ float sp[2];
    if (lane == 0) sp[wave] = v;
    __syncthreads();
    if (t == 0) out[blockIdx.x] = (sp[0] + sp[1]) * 13.86294361f;  // 2*WALL*ln2
}

extern "C" void kernel_launch(void* const* d_in, const int* in_sizes, int n_in,
                              void* d_out, int out_size, void* d_ws, size_t ws_size,
                              hipStream_t stream) {
    (void)n_in; (void)out_size; (void)ws_size;
    const float* R = (const float*)d_in[0];
    float* out = (float*)d_out;
    float* ws  = (float*)d_ws;

    const int B = in_sizes[0] / (LPTS * 3);
    pair_energy_kernel<<<B * 128, 512, 0, stream>>>(R, ws);  // 8 row-pair units / block
    reduce_kernel<<<B, 128, 0, stream>>>(ws, out);           // 128 partials / batch
}